// Round 8
// baseline (80.704 us; speedup 1.0000x reference)
//
#include <hip/hip_runtime.h>
#include <hip/hip_fp16.h>

// Problem dims (fixed by setup_inputs):
//   key_frame: (B=4, C=64, 1, H=128, W=256) f32
//   flow:      (B=4, 2, T=8, H=128, W=256)  f32
//   out:       (B=4, C=64, T=8, H=128, W=256) f32
#define B_ 4
#define C_ 64
#define T_ 8
#define H_ 128
#define W_ 256
#define HW_ (H_ * W_)

typedef float f32x4 __attribute__((ext_vector_type(4)));

// ---------------------------------------------------------------------------
// Kernel 1: transpose key_frame (B,C,H,W) f32 -> (B,H*W,C) f16.
// Pixel block = 64 ch * 2B = 128B; (x0,x0+1) corner pair = 256B contiguous.
// ---------------------------------------------------------------------------
__global__ __launch_bounds__(256) void kf_transpose_f16_kernel(const float* __restrict__ kf,
                                                               __half2* __restrict__ kfh2) {
  __shared__ float tile[64][65];  // +1 pad
  int bid  = blockIdx.x;          // b * (HW/64) + chunk
  int b    = bid >> 9;            // HW_/64 = 512 chunks per b
  int p0   = (bid & 511) << 6;    // first pixel of this 64-pixel chunk
  int lane = threadIdx.x & 63;
  int grp  = threadIdx.x >> 6;    // 0..3

  const float* src = kf + (size_t)b * C_ * HW_ + p0 + lane;
#pragma unroll
  for (int k = 0; k < 16; ++k) {
    int c = grp * 16 + k;
    tile[c][lane] = src[(size_t)c * HW_];     // coalesced along pixels
  }
  __syncthreads();
  int m  = lane & 31;
  int ph = lane >> 5;             // 0/1: which of the two pixels
#pragma unroll
  for (int k = 0; k < 8; ++k) {
    int p = grp * 16 + 2 * k + ph;
    __half2 h = __floats2half2_rn(tile[2 * m][p], tile[2 * m + 1][p]);
    kfh2[((size_t)b * HW_ + p0 + p) * 32 + m] = h;
  }
}

// ---------------------------------------------------------------------------
// Kernel 2: warp. One block = 256 threads = one FULL (b,t,h) row (256 px).
// Phase 0: every thread computes its own pixel's bases/weights -> LDS.
// Phase 1: per wave, 2 pixels/iter: (v00,v01) pair = one 256B dword wave-load;
//          permlane32_swap un-interleaves (R4 hardware-proven); lerp in f32;
//          each lane writes its two result channels (2m, 2m+1) of pixel p
//          directly into the f16 [c][w] LDS layout (two ds_write_b16) —
//          NO cross-lane movement in the pack path.
// Phase 2: per c: ds_read 8B (4 halves) -> cvt -> ONE 1KB float4 wave-store.
// ---------------------------------------------------------------------------
__global__ __launch_bounds__(256, 4) void warp_kernel(const float* __restrict__ flow,
                                                      const uint* __restrict__ kfu,
                                                      float* __restrict__ out) {
  __shared__ int    s_bT[256], s_bB[256];
  __shared__ float  s_wx[256], s_wy[256];
  __shared__ __half s_val[64 * 260];  // f16 [c][w]: row stride 260 halves (256+4 pad)

  // --- XCD-aware work decode (grid = 4096 = B*T*H) ---
  int bid = blockIdx.x;
  int xcd = bid & 7;              // (b, h-half) per XCD: 2MB f16 hot set = L2-fit
  int idx = bid >> 3;             // 0..511 within this XCD
  int b   = xcd >> 1;
  int hh  = xcd & 1;
  int t   = idx & 7;              // t innermost: same pixels, 8 flows in a row
  int hl  = idx >> 3;             // 0..63
  int h   = (hh << 6) + hl;

  int tid  = threadIdx.x;
  int lane = tid & 63;
  int wv   = tid >> 6;

  // Phase 0: thread = pixel w = tid
  {
    int w = tid;
    size_t fbase = ((size_t)b * 2 * T_ + t) * HW_ + (size_t)h * W_ + w;
    float fx = flow[fbase];                    // flow[b][0][t][h][w]
    float fy = flow[fbase + (size_t)T_ * HW_]; // flow[b][1][t][h][w]
    float cx = (float)w + fx;
    float cy = (float)h + fy;
    float gx = 2.0f * cx / (float)(W_ - 1) - 1.0f;
    float gy = 2.0f * cy / (float)(H_ - 1) - 1.0f;
    float ix = (gx + 1.0f) * 0.5f * (float)(W_ - 1);
    float iy = (gy + 1.0f) * 0.5f * (float)(H_ - 1);
    ix = fminf(fmaxf(ix, 0.0f), (float)(W_ - 1));
    iy = fminf(fmaxf(iy, 0.0f), (float)(H_ - 1));
    float x0f = floorf(ix);
    float y0f = floorf(iy);
    s_wx[tid] = ix - x0f;   // == 0 whenever x0 clamps to W-1 (v01 don't-care)
    s_wy[tid] = iy - y0f;   // == 0 whenever y0 clamps to H-1 (bot don't-care)
    int x0 = min(max((int)x0f, 0), W_ - 1);
    int y0 = min(max((int)y0f, 0), H_ - 1);
    int y1 = min(y0 + 1, H_ - 1);
    s_bT[tid] = (b * HW_ + y0 * W_ + x0) << 5;  // dword idx of 256B pair base
    s_bB[tid] = (b * HW_ + y1 * W_ + x0) << 5;  // (x0=W-1 over-reads 128B, wx=0)
  }
  __syncthreads();

  int half = lane >> 5;           // 0: pixel A, 1: pixel B
  int m    = lane & 31;           // channel pair (2m, 2m+1)
  int p0   = wv << 6;             // this wave's 64-pixel quarter

#pragma unroll 4
  for (int j = 0; j < 32; ++j) {
    int pA = p0 + 2 * j;
    int pB = pA + 1;
    uint aT = kfu[s_bT[pA] + lane];   // [v00A | v01A]
    uint bT = kfu[s_bT[pB] + lane];   // [v00B | v01B]
    uint aB = kfu[s_bB[pA] + lane];   // [v10A | v11A]
    uint bB = kfu[s_bB[pB] + lane];   // [v10B | v11B]
    asm volatile("v_permlane32_swap_b32 %0, %1" : "+v"(aT), "+v"(bT));
    asm volatile("v_permlane32_swap_b32 %0, %1" : "+v"(aB), "+v"(bB));
    // per lane: aT=v00, bT=v01, aB=v10, bB=v11 of pixel p = pA + half
    int p = pA + half;
    float wx = s_wx[p];
    float wy = s_wy[p];
    float2 f00 = __half22float2(*(__half2*)&aT);
    float2 f01 = __half22float2(*(__half2*)&bT);
    float2 f10 = __half22float2(*(__half2*)&aB);
    float2 f11 = __half22float2(*(__half2*)&bB);
    float top0 = f00.x + wx * (f01.x - f00.x);
    float top1 = f00.y + wx * (f01.y - f00.y);
    float bot0 = f10.x + wx * (f11.x - f10.x);
    float bot1 = f10.y + wx * (f11.y - f10.y);
    float r0 = top0 + wy * (bot0 - top0);   // channel 2m of pixel p
    float r1 = top1 + wy * (bot1 - top1);   // channel 2m+1 of pixel p
    // Direct f16 [c][w] placement — no cross-lane movement needed.
    __half2 hp = __floats2half2_rn(r0, r1);
    s_val[(2 * m) * 260 + p]     = __low2half(hp);
    s_val[(2 * m + 1) * 260 + p] = __high2half(hp);
  }
  __syncthreads();

  // Phase 2: c = wv*16 + k; one 1KB float4 wave-store per channel row
#pragma unroll
  for (int k = 0; k < 16; ++k) {
    int c = (wv << 4) + k;
    uint2 uu = *(const uint2*)((const uint*)s_val + c * 130 + 2 * lane);  // w 4l..4l+3
    float2 va = __half22float2(*(__half2*)&uu.x);
    float2 vb = __half22float2(*(__half2*)&uu.y);
    f32x4 v = {va.x, va.y, vb.x, vb.y};
    f32x4* dst = (f32x4*)(out + ((((size_t)b * C_ + c) * T_ + t) * H_ + h) * W_ + 4 * lane);
    __builtin_nontemporal_store(v, dst);
  }
}

// ---------------------------------------------------------------------------
// Fallback (only if ws too small): direct per-output-element gather. Slow.
// ---------------------------------------------------------------------------
__global__ __launch_bounds__(256) void warp_naive_kernel(const float* __restrict__ kf,
                                                         const float* __restrict__ flow,
                                                         float* __restrict__ out) {
  size_t idx = (size_t)blockIdx.x * 256 + threadIdx.x;
  int w = (int)(idx & (W_ - 1));
  int h = (int)((idx >> 8) & (H_ - 1));
  int t = (int)((idx >> 15) & (T_ - 1));
  int c = (int)((idx >> 18) & (C_ - 1));
  int b = (int)(idx >> 24);

  size_t fbase = ((size_t)b * 2 * T_ + t) * HW_ + (size_t)h * W_ + w;
  float fx = flow[fbase];
  float fy = flow[fbase + (size_t)T_ * HW_];
  float cx = (float)w + fx;
  float cy = (float)h + fy;
  float gx = 2.0f * cx / (float)(W_ - 1) - 1.0f;
  float gy = 2.0f * cy / (float)(H_ - 1) - 1.0f;
  float ix = (gx + 1.0f) * 0.5f * (float)(W_ - 1);
  float iy = (gy + 1.0f) * 0.5f * (float)(H_ - 1);
  ix = fminf(fmaxf(ix, 0.0f), (float)(W_ - 1));
  iy = fminf(fmaxf(iy, 0.0f), (float)(H_ - 1));
  float x0f = floorf(ix);
  float y0f = floorf(iy);
  float wx = ix - x0f;
  float wy = iy - y0f;
  int x0 = min(max((int)x0f, 0), W_ - 1);
  int y0 = min(max((int)y0f, 0), H_ - 1);
  int x1 = min(x0 + 1, W_ - 1);
  int y1 = min(y0 + 1, H_ - 1);

  const float* src = kf + ((size_t)b * C_ + c) * HW_;
  float v00 = src[y0 * W_ + x0];
  float v01 = src[y0 * W_ + x1];
  float v10 = src[y1 * W_ + x0];
  float v11 = src[y1 * W_ + x1];
  float top = v00 + wx * (v01 - v00);
  float bot = v10 + wx * (v11 - v10);
  out[idx] = top + wy * (bot - top);
}

extern "C" void kernel_launch(void* const* d_in, const int* in_sizes, int n_in,
                              void* d_out, int out_size, void* d_ws, size_t ws_size,
                              hipStream_t stream) {
  const float* kf   = (const float*)d_in[0];  // key_frame
  const float* flow = (const float*)d_in[1];  // output_flow
  float* out = (float*)d_out;

  const size_t need = (size_t)B_ * C_ * HW_ * sizeof(__half) + 4096;  // 16 MiB + OOB slack
  if (ws_size >= need) {
    __half* kfh = (__half*)d_ws;
    hipLaunchKernelGGL(kf_transpose_f16_kernel, dim3(B_ * (HW_ / 64)), dim3(256), 0, stream,
                       kf, (__half2*)kfh);
    hipLaunchKernelGGL(warp_kernel, dim3(B_ * T_ * H_), dim3(256), 0, stream,
                       flow, (const uint*)kfh, out);
  } else {
    const size_t total = (size_t)B_ * C_ * T_ * HW_;
    hipLaunchKernelGGL(warp_naive_kernel, dim3((unsigned)(total / 256)), dim3(256), 0, stream,
                       kf, flow, out);
  }
}